// Round 22
// baseline (429.935 us; speedup 1.0000x reference)
//
#include <hip/hip_runtime.h>
#include <hip/hip_bf16.h>
#include <math.h>

#define L_  4096
#define D_  256
#define DI_ 512
#define NS_ 16
#define NC_ 256
#define CH_ 16
#define NSEG_ 16

typedef __attribute__((ext_vector_type(8))) short short8;
typedef __attribute__((ext_vector_type(4))) short short4v;
typedef __attribute__((ext_vector_type(4))) float f32x4;

// ---------------- prep: embed + all weight converts in one dispatch ----------------
__global__ __launch_bounds__(256) void prep_kernel(const int* __restrict__ ids,
    const float* __restrict__ ew, const float* __restrict__ inw,
    const float* __restrict__ outw, const float* __restrict__ xpw,
    float* __restrict__ res, __hip_bfloat16* __restrict__ inw_b,
    __hip_bfloat16* __restrict__ outw_b, __hip_bfloat16* __restrict__ xpw_b) {
  int idx = blockIdx.x * 256 + threadIdx.x;          // 0 .. 1048575
  int l = idx >> 8, d = idx & 255;
  res[idx] = ew[ids[l] * D_ + d];
  inw_b[idx] = __float2bfloat16(inw[idx]);           // 4*1024*256 = 1048576
  {                                                  // duplicated-K out_proj [4][256][1024]
    int layer = idx >> 18;
    int rem = idx & 262143;
    int o = rem >> 10, k = rem & 1023;
    outw_b[idx] = __float2bfloat16(outw[((size_t)layer * 256 + o) * 512 + (k & 511)]);
  }
  if (idx < 4 * 2 * 64 * 512) {                      // padded [4][2][64][512]
    int layer = idx >> 16;
    int rem = idx & 65535;
    int dir = rem >> 15;
    int r = (rem >> 9) & 63, k = idx & 511;
    float v = (r < 48) ? xpw[(((size_t)layer * 2 + dir) * 48 + r) * 512 + k] : 0.f;
    xpw_b[idx] = __float2bfloat16(v);
  }
}

// ---------------- rmsnorm: wave-per-row, float4 ----------------
template<bool BF16OUT>
__global__ __launch_bounds__(256) void rmsnorm_kernel(float* __restrict__ residual,
    const float* __restrict__ hadd, const float* __restrict__ w, void* __restrict__ out) {
  int row = blockIdx.x * 4 + (threadIdx.x >> 6);
  int lane = threadIdx.x & 63;
  size_t o = (size_t)row * D_ + lane * 4;
  float4 v = *(const float4*)(residual + o);
  if (hadd) {
    float4 a = *(const float4*)(hadd + o);
    v.x += a.x; v.y += a.y; v.z += a.z; v.w += a.w;
    *(float4*)(residual + o) = v;
  }
  float sq = fmaf(v.x, v.x, fmaf(v.y, v.y, fmaf(v.z, v.z, v.w * v.w)));
  #pragma unroll
  for (int s = 32; s > 0; s >>= 1) sq += __shfl_xor(sq, s, 64);
  float scale = rsqrtf(sq * (1.f / D_) + 1e-5f);
  float4 wv = *(const float4*)(w + lane * 4);
  float r0 = v.x * scale * wv.x, r1 = v.y * scale * wv.y;
  float r2 = v.z * scale * wv.z, r3 = v.w * scale * wv.w;
  if (BF16OUT) {
    __hip_bfloat16* ob = (__hip_bfloat16*)out + o;
    short4v s4;
    s4[0] = __bfloat16_as_short(__float2bfloat16(r0));
    s4[1] = __bfloat16_as_short(__float2bfloat16(r1));
    s4[2] = __bfloat16_as_short(__float2bfloat16(r2));
    s4[3] = __bfloat16_as_short(__float2bfloat16(r3));
    *reinterpret_cast<short4v*>(ob) = s4;
  } else {
    float4 r = {r0, r1, r2, r3};
    *((float4*)out + (o >> 2)) = r;
  }
}

// ---------------- bf16 MFMA GEMM: C[m,n] = sum_k A[m,k]*B[n,k] (B^T layout) ----------------
__device__ __forceinline__ void gload_lds16(const void* g, void* l) {
  __builtin_amdgcn_global_load_lds((const __attribute__((address_space(1))) unsigned int*)g,
                                   (__attribute__((address_space(3))) unsigned int*)l,
                                   16, 0, 0);
}

template<int BM, int BN, bool BF16OUT>
__global__ __launch_bounds__(256) void gemm_bt_bf16(const __hip_bfloat16* __restrict__ A,
    const __hip_bfloat16* __restrict__ B, void* __restrict__ Cv, int M, int N, int K,
    size_t sA, size_t sB, size_t sC) {
  A += (size_t)blockIdx.z * sA; B += (size_t)blockIdx.z * sB;
  constexpr int FM = (BM / 2) / 16, FN = (BN / 2) / 16;
  constexpr int ABYTES = BM * 64, BBYTES = BN * 64;
  __shared__ __attribute__((aligned(16))) char As[ABYTES];
  __shared__ __attribute__((aligned(16))) char Bs[BBYTES];
  int tid = threadIdx.x, lane = tid & 63, w = tid >> 6;
  int bm = blockIdx.y * BM, bn = blockIdx.x * BN;
  int wr = (w >> 1) * (BM / 2), wc = (w & 1) * (BN / 2);
  f32x4 acc[FM][FN] = {};
  for (int k0 = 0; k0 < K; k0 += 32) {
    __syncthreads();
    #pragma unroll
    for (int i = 0; i < ABYTES / 4096; ++i) {
      int x = (i * 256 + tid) * 16;
      int xs = x ^ (((x >> 7) & 3) << 4);
      int row = xs >> 6, col = (xs & 63) >> 1;
      gload_lds16(A + (size_t)(bm + row) * K + k0 + col, As + i * 4096 + w * 1024);
    }
    #pragma unroll
    for (int i = 0; i < BBYTES / 4096; ++i) {
      int x = (i * 256 + tid) * 16;
      int xs = x ^ (((x >> 7) & 3) << 4);
      int row = xs >> 6, col = (xs & 63) >> 1;
      gload_lds16(B + (size_t)(bn + row) * K + k0 + col, Bs + i * 4096 + w * 1024);
    }
    __syncthreads();
    short8 af[FM], bf[FN];
    #pragma unroll
    for (int m = 0; m < FM; ++m) {
      int row = wr + m * 16 + (lane & 15);
      int x = row * 64 + ((lane >> 4) * 16);
      x ^= ((x >> 7) & 3) << 4;
      af[m] = *reinterpret_cast<const short8*>(As + x);
    }
    #pragma unroll
    for (int n = 0; n < FN; ++n) {
      int row = wc + n * 16 + (lane & 15);
      int x = row * 64 + ((lane >> 4) * 16);
      x ^= ((x >> 7) & 3) << 4;
      bf[n] = *reinterpret_cast<const short8*>(Bs + x);
    }
    #pragma unroll
    for (int m = 0; m < FM; ++m)
      #pragma unroll
      for (int n = 0; n < FN; ++n)
        acc[m][n] = __builtin_amdgcn_mfma_f32_16x16x32_bf16(af[m], bf[n], acc[m][n], 0, 0, 0);
  }
  #pragma unroll
  for (int m = 0; m < FM; ++m)
    #pragma unroll
    for (int n = 0; n < FN; ++n)
      #pragma unroll
      for (int j = 0; j < 4; ++j) {
        size_t off = (size_t)blockIdx.z * sC +
                     (size_t)(bm + wr + m * 16 + (lane >> 4) * 4 + j) * N + bn + wc + n * 16 + (lane & 15);
        if (BF16OUT) ((__hip_bfloat16*)Cv)[off] = __float2bfloat16(acc[m][n][j]);
        else         ((float*)Cv)[off] = acc[m][n][j];
      }
}

// ---------------- xproj_conv_scan (CH=16): conv+SiLU -> su/uc; GEMM -> xdb; pass1 in-place ----------------
// LDS union (37 KB): sxz[20][512] dead after conv; Bs aliased [0,4K), sxdb [4K,8K); su at [20480,...)
__global__ __launch_bounds__(256) void xproj_conv_scan(const __hip_bfloat16* __restrict__ xz,
    const float* __restrict__ cw, const float* __restrict__ cb,
    const __hip_bfloat16* __restrict__ xpw_b, const float* __restrict__ dtw,
    const float* __restrict__ dtbp, const float* __restrict__ A_log,
    float* __restrict__ xdb, __hip_bfloat16* __restrict__ ucb,
    float* __restrict__ Pb, float* __restrict__ Qb) {
  int dir = blockIdx.y;
  int l0 = blockIdx.x * CH_;                     // chunk c = blockIdx.x (CH=16)
  int tid = threadIdx.x, lane = tid & 63, w = tid >> 6;
  __shared__ __attribute__((aligned(16))) char smem[37120];
  unsigned short (*sxz)[512] = (unsigned short(*)[512])smem;            // [20][512]
  unsigned short (*su)[520]  = (unsigned short(*)[520])(smem + 20480);  // [16][520]
  char* Bs = smem;                                                       // 4 KB alias
  float (*sxdb)[64] = (float(*)[64])(smem + 4096);                       // [16][64] alias
  // stage xz window: slot s holds frame l0-3+s (s=0..18; s=19 dup, unread)
  #pragma unroll
  for (int it = 0; it < 5; ++it) {
    int s = it * 4 + w;
    int sc = s > 18 ? 18 : s;
    int f = l0 - 3 + sc;
    int row = dir ? (L_ - 1 - f) : f;
    row = row < 0 ? 0 : (row > L_ - 1 ? L_ - 1 : row);
    gload_lds16((const char*)xz + (size_t)row * 2048 + lane * 16, (char*)sxz + s * 1024);
  }
  __syncthreads();
  // u = silu(conv) -> su (bf16) + stream to global uc_b
  unsigned short* ucs = (unsigned short*)ucb;
  #pragma unroll
  for (int half = 0; half < 2; ++half) {
    int ch = half * 256 + tid;
    float4 wv = *(const float4*)(cw + ((size_t)dir * DI_ + ch) * 4);
    float bias = cb[(size_t)dir * DI_ + ch];
    #pragma unroll 4
    for (int t = 0; t < CH_; ++t) {
      float acc = bias;
      #pragma unroll
      for (int k = 0; k < 4; ++k) {
        float xv = (l0 == 0 && t + k < 3) ? 0.f
                 : __uint_as_float((unsigned)sxz[t + k][ch] << 16);
        acc = fmaf(((const float*)&wv)[k], xv, acc);
      }
      float uvf = acc * __builtin_amdgcn_rcpf(1.f + __expf(-acc));
      unsigned short bits = (unsigned short)__bfloat16_as_short(__float2bfloat16(uvf));
      su[t][ch] = bits;
      ucs[((size_t)dir * L_ + l0 + t) * DI_ + ch] = bits;
    }
  }
  // GEMM: A = su (16 rows, full K=512 in LDS), B = xpw staged per k-step; wave w owns cols w*16..
  const __hip_bfloat16* B = xpw_b + (size_t)dir * 64 * 512;
  int wc = w * 16;
  f32x4 acc2 = {};
  for (int k0 = 0; k0 < 512; k0 += 32) {
    __syncthreads();
    {
      int x = tid * 16;
      int xs = x ^ (((x >> 7) & 3) << 4);
      int row = xs >> 6, col = (xs & 63) >> 1;
      gload_lds16(B + (size_t)row * 512 + k0 + col, Bs + w * 1024);
    }
    __syncthreads();
    short8 af = *reinterpret_cast<const short8*>(
        (const char*)su + (lane & 15) * 1040 + (k0 + (lane >> 4) * 8) * 2);
    {
      int row = wc + (lane & 15);
      int x = row * 64 + ((lane >> 4) * 16);
      x ^= ((x >> 7) & 3) << 4;
      short8 bf8 = *reinterpret_cast<const short8*>(Bs + x);
      acc2 = __builtin_amdgcn_mfma_f32_16x16x32_bf16(af, bf8, acc2, 0, 0, 0);
    }
  }
  // write xdb tile to global AND to LDS sxdb (aliases dead sxz region)
  #pragma unroll
  for (int j = 0; j < 4; ++j) {
    int tt = (lane >> 4) * 4 + j;
    int col = wc + (lane & 15);
    xdb[((size_t)dir * L_ + l0 + tt) * 64 + col] = acc2[j];
    sxdb[tt][col] = acc2[j];
  }
  __syncthreads();
  // ---- pass1 in-place: 2 sequential channel halves, 16 states each ----
  size_t pqbase = ((size_t)dir * NC_ + blockIdx.x) * 8192;
  #pragma unroll
  for (int half = 0; half < 2; ++half) {
    int ch = half * 256 + tid;
    const float4* wr4 = (const float4*)(dtw + ((size_t)dir * DI_ + ch) * 16);
    float4 w0 = wr4[0], w1 = wr4[1], w2 = wr4[2], w3 = wr4[3];
    float bias = dtbp[(size_t)dir * DI_ + ch];
    const float4* Ab4 = (const float4*)(A_log + ((size_t)dir * DI_ + ch) * 16);
    float4 a0 = Ab4[0], a1 = Ab4[1], a2 = Ab4[2], a3 = Ab4[3];
    float Av[16] = {a0.x, a0.y, a0.z, a0.w, a1.x, a1.y, a1.z, a1.w,
                    a2.x, a2.y, a2.z, a2.w, a3.x, a3.y, a3.z, a3.w};
    #pragma unroll
    for (int n = 0; n < 16; ++n) Av[n] = -__expf(Av[n]);
    float P[16], Q[16];
    #pragma unroll
    for (int n = 0; n < 16; ++n) { P[n] = 1.f; Q[n] = 0.f; }
    #pragma unroll 2
    for (int t = 0; t < CH_; ++t) {
      const float4* xr = (const float4*)&sxdb[t][0];
      float4 x0 = xr[0], x1 = xr[1], x2 = xr[2], x3 = xr[3];
      float accd = bias;
      accd = fmaf(w0.x, x0.x, fmaf(w0.y, x0.y, fmaf(w0.z, x0.z, fmaf(w0.w, x0.w, accd))));
      accd = fmaf(w1.x, x1.x, fmaf(w1.y, x1.y, fmaf(w1.z, x1.z, fmaf(w1.w, x1.w, accd))));
      accd = fmaf(w2.x, x2.x, fmaf(w2.y, x2.y, fmaf(w2.z, x2.z, fmaf(w2.w, x2.w, accd))));
      accd = fmaf(w3.x, x3.x, fmaf(w3.y, x3.y, fmaf(w3.z, x3.z, fmaf(w3.w, x3.w, accd))));
      float e = __expf(fminf(accd, 20.f));
      float dtv = accd > 20.f ? accd : __logf(1.f + e);
      float uv = __uint_as_float((unsigned)su[t][ch] << 16);
      float du = dtv * uv;
      const float4* Br4 = (const float4*)&sxdb[t][16];
      float4 B0 = Br4[0], B1 = Br4[1], B2 = Br4[2], B3 = Br4[3];
      float bb[16] = {B0.x, B0.y, B0.z, B0.w, B1.x, B1.y, B1.z, B1.w,
                      B2.x, B2.y, B2.z, B2.w, B3.x, B3.y, B3.z, B3.w};
      #pragma unroll
      for (int n = 0; n < 16; ++n) {
        float dA = __expf(dtv * Av[n]);
        P[n] *= dA;
        Q[n] = fmaf(dA, Q[n], bb[n] * du);
      }
    }
    #pragma unroll
    for (int n = 0; n < 16; ++n) {
      Pb[pqbase + n * 512 + ch] = P[n];
      Qb[pqbase + n * 512 + ch] = Q[n];
    }
  }
}

// ---- staging (CH=16): sxdb[16][64] + su[16][128] from global; dt computed in-LDS ----
__device__ __forceinline__ void scan_stage3(int tid, int lane, int w, int q, int dir, int c,
    const float* __restrict__ xdb, const __hip_bfloat16* __restrict__ uc,
    const float* __restrict__ dtw, const float* __restrict__ dtbp,
    float (*sxdb)[64], unsigned short (*su)[128], float (*sdt)[128]) {
  const char* bg = (const char*)(xdb + ((size_t)dir * L_ + (size_t)c * CH_) * 64);
  const char* ug = (const char*)(uc + ((size_t)dir * L_ + (size_t)c * CH_) * DI_ + q * 128);
  gload_lds16(bg + tid * 16, (char*)sxdb + w * 1024);       // 4 KB contiguous
  {
    int byte = tid * 16;                                    // su rows: 256B @ stride 1024B
    gload_lds16(ug + (byte >> 8) * 1024 + (byte & 255), (char*)su + w * 1024);
  }
  __syncthreads();
  int dlx = tid & 127, tst = tid >> 7;
  int dc = q * 128 + dlx;
  const float4* wr = (const float4*)(dtw + ((size_t)dir * DI_ + dc) * 16);
  float4 w0 = wr[0], w1 = wr[1], w2 = wr[2], w3 = wr[3];
  float bias = dtbp[(size_t)dir * DI_ + dc];
  #pragma unroll
  for (int i = 0; i < 8; ++i) {
    int t = tst + i * 2;
    const float4* xr = (const float4*)&sxdb[t][0];
    float4 x0 = xr[0], x1 = xr[1], x2 = xr[2], x3 = xr[3];
    float acc = bias;
    acc = fmaf(w0.x, x0.x, fmaf(w0.y, x0.y, fmaf(w0.z, x0.z, fmaf(w0.w, x0.w, acc))));
    acc = fmaf(w1.x, x1.x, fmaf(w1.y, x1.y, fmaf(w1.z, x1.z, fmaf(w1.w, x1.w, acc))));
    acc = fmaf(w2.x, x2.x, fmaf(w2.y, x2.y, fmaf(w2.z, x2.z, fmaf(w2.w, x2.w, acc))));
    acc = fmaf(w3.x, x3.x, fmaf(w3.y, x3.y, fmaf(w3.z, x3.z, fmaf(w3.w, x3.w, acc))));
    float e = __expf(fminf(acc, 20.f));
    sdt[t][dlx] = acc > 20.f ? acc : __logf(1.f + e);
  }
  __syncthreads();
}

// ---------------- combine (two-level segmented): 16 segs x 16 chunks ----------------
__global__ __launch_bounds__(256) void combine_a(const float* __restrict__ Pb,
    const float* __restrict__ Qb, float* __restrict__ Pseg, float* __restrict__ Qseg) {
  int chain = blockIdx.x * 256 + threadIdx.x;   // 0..16383
  int seg = blockIdx.y;                          // 0..15
  int dir = chain >> 13, s = chain & 8191;
  size_t base = (size_t)dir * NC_ * 8192 + s;
  float P = 1.f, Q = 0.f;
  #pragma unroll 16
  for (int cc = 0; cc < 16; ++cc) {
    size_t o = base + (size_t)(seg * 16 + cc) * 8192;
    float p = Pb[o], q = Qb[o];
    Q = fmaf(p, Q, q);
    P *= p;
  }
  Pseg[seg * 16384 + chain] = P;
  Qseg[seg * 16384 + chain] = Q;
}

__global__ __launch_bounds__(256) void combine_c(const float* __restrict__ Pb,
    const float* __restrict__ Qb, const float* __restrict__ Pseg,
    const float* __restrict__ Qseg, float* __restrict__ H0) {
  int chain = blockIdx.x * 256 + threadIdx.x;
  int seg = blockIdx.y;
  int dir = chain >> 13, s = chain & 8191;
  size_t base = (size_t)dir * NC_ * 8192 + s;
  float h = 0.f;
  for (int s2 = 0; s2 < seg; ++s2)
    h = fmaf(Pseg[s2 * 16384 + chain], h, Qseg[s2 * 16384 + chain]);
  #pragma unroll 16
  for (int cc = 0; cc < 16; ++cc) {
    size_t o = base + (size_t)(seg * 16 + cc) * 8192;
    H0[o] = h;
    h = fmaf(Pb[o], h, Qb[o]);
  }
}

// ---------------- scan pass2 (CH=16) ----------------
__global__ __launch_bounds__(256) void scan_pass2(const __hip_bfloat16* __restrict__ uc,
    const float* __restrict__ xdb, const float* __restrict__ dtw,
    const float* __restrict__ dtbp, const float* __restrict__ A_log,
    const float* __restrict__ Dp, const __hip_bfloat16* __restrict__ xz,
    const float* __restrict__ H0, __hip_bfloat16* __restrict__ yg) {
  int dir = blockIdx.y;
  int c = blockIdx.x >> 2, q = blockIdx.x & 3;
  int tid = threadIdx.x, lane = tid & 63, w = tid >> 6;
  int dl = tid >> 1, nh = tid & 1;
  int d = q * 128 + dl;
  __shared__ __attribute__((aligned(16))) float sxdb[CH_][64];          // 4 KB
  __shared__ __attribute__((aligned(16))) unsigned short su[CH_][128];  // 4 KB
  __shared__ __attribute__((aligned(16))) float sdt[CH_][128];          // 8 KB
  float Av[8], h[8];
  const float4* Ab4 = (const float4*)(A_log + ((size_t)dir * DI_ + d) * 16 + nh * 8);
  float4 a0 = Ab4[0], a1 = Ab4[1];
  float al[8] = {a0.x, a0.y, a0.z, a0.w, a1.x, a1.y, a1.z, a1.w};
  size_t ob = ((size_t)dir * NC_ + c) * 8192 + (size_t)(nh * 8) * 512 + d;
  #pragma unroll
  for (int j = 0; j < 8; ++j) { Av[j] = -__expf(al[j]); h[j] = H0[ob + j * 512]; }
  float Dv = Dp[(size_t)dir * DI_ + d];
  scan_stage3(tid, lane, w, q, dir, c, xdb, uc, dtw, dtbp, sxdb, su, sdt);
  #pragma unroll 8
  for (int t = 0; t < CH_; ++t) {
    float dtv = sdt[t][dl];
    float uv  = __uint_as_float((unsigned)su[t][dl] << 16);
    float du = dtv * uv;
    const float4* Br = (const float4*)&sxdb[t][16 + nh * 8];
    const float4* Cr = (const float4*)&sxdb[t][32 + nh * 8];
    float4 b0 = Br[0], b1 = Br[1], c0 = Cr[0], c1 = Cr[1];
    float bb[8] = {b0.x, b0.y, b0.z, b0.w, b1.x, b1.y, b1.z, b1.w};
    float cc[8] = {c0.x, c0.y, c0.z, c0.w, c1.x, c1.y, c1.z, c1.w};
    float y = 0.f;
    #pragma unroll
    for (int j = 0; j < 8; ++j) {
      float dA = __expf(dtv * Av[j]);
      h[j] = fmaf(dA, h[j], bb[j] * du);
      y = fmaf(h[j], cc[j], y);
    }
    y += __shfl_xor(y, 1, 64);
    if (nh == 0) {
      int l = c * CH_ + t;
      int pos = dir ? (L_ - 1 - l) : l;
      float zv = __bfloat162float(xz[(size_t)pos * 1024 + DI_ + d]);
      float g = zv * __builtin_amdgcn_rcpf(1.f + __expf(-zv));
      yg[(size_t)pos * 1024 + (size_t)dir * DI_ + d] = __float2bfloat16((y + uv * Dv) * g);
    }
  }
}

extern "C" void kernel_launch(void* const* d_in, const int* in_sizes, int n_in,
                              void* d_out, int out_size, void* d_ws, size_t ws_size,
                              hipStream_t stream) {
  const int*   ids       = (const int*)  d_in[0];
  const float* embed_w   = (const float*)d_in[1];
  const float* norm_w    = (const float*)d_in[2];
  const float* in_proj_w = (const float*)d_in[3];
  const float* out_proj_w= (const float*)d_in[4];
  const float* conv_w    = (const float*)d_in[5];
  const float* conv_b    = (const float*)d_in[6];
  const float* x_proj_w  = (const float*)d_in[7];
  const float* dt_proj_w = (const float*)d_in[8];
  const float* dt_proj_b = (const float*)d_in[9];
  const float* A_log     = (const float*)d_in[10];
  const float* Dp        = (const float*)d_in[11];
  const float* norm_f_w  = (const float*)d_in[12];

  float* ws = (float*)d_ws;
  float* residual = ws; ws += (size_t)L_ * D_;
  float* xdb      = ws; ws += (size_t)2 * L_ * 64;
  float* hbuf     = ws; ws += (size_t)L_ * D_;
  float* Pb       = ws; ws += (size_t)2 * NC_ * 8192;
  float* Qb       = ws; ws += (size_t)2 * NC_ * 8192;
  float* H0       = ws; ws += (size_t)2 * NC_ * 8192;
  float* Pseg     = ws; ws += (size_t)NSEG_ * 16384;
  float* Qseg     = ws; ws += (size_t)NSEG_ * 16384;
  __hip_bfloat16* hn_b   = (__hip_bfloat16*)ws;
  __hip_bfloat16* xz_b   = hn_b + (size_t)L_ * D_;
  __hip_bfloat16* yg_b   = xz_b + (size_t)L_ * 1024;     // [pos][dir*512+d]
  __hip_bfloat16* uc_b   = yg_b + (size_t)L_ * 1024;
  __hip_bfloat16* inw_b  = uc_b + (size_t)2 * L_ * DI_;
  __hip_bfloat16* outw_b = inw_b + (size_t)4 * 1024 * D_;
  __hip_bfloat16* xpw_b  = outw_b + (size_t)4 * D_ * 1024;

  prep_kernel<<<L_ * D_ / 256, 256, 0, stream>>>(ids, embed_w, in_proj_w, out_proj_w,
                                                 x_proj_w, residual, inw_b, outw_b, xpw_b);

  for (int i = 0; i < 4; ++i) {
    rmsnorm_kernel<true><<<L_ / 4, 256, 0, stream>>>(residual, i ? hbuf : nullptr,
                                                     norm_w + (size_t)i * D_, hn_b);
    gemm_bt_bf16<128, 64, true><<<dim3(1024 / 64, L_ / 128, 1), 256, 0, stream>>>(
        hn_b, inw_b + (size_t)i * 1024 * D_, xz_b, L_, 1024, D_, 0, 0, 0);
    xproj_conv_scan<<<dim3(L_ / CH_, 2), 256, 0, stream>>>(
        xz_b, conv_w + (size_t)i * 2 * DI_ * 4, conv_b + (size_t)i * 2 * DI_,
        xpw_b + (size_t)i * 2 * 64 * DI_, dt_proj_w + (size_t)i * 2 * DI_ * 16,
        dt_proj_b + (size_t)i * 2 * DI_, A_log + (size_t)i * 2 * DI_ * NS_,
        xdb, uc_b, Pb, Qb);
    combine_a<<<dim3(64, NSEG_), 256, 0, stream>>>(Pb, Qb, Pseg, Qseg);
    combine_c<<<dim3(64, NSEG_), 256, 0, stream>>>(Pb, Qb, Pseg, Qseg, H0);
    scan_pass2<<<dim3(NC_ * 4, 2), 256, 0, stream>>>(
        uc_b, xdb, dt_proj_w + (size_t)i * 2 * DI_ * 16, dt_proj_b + (size_t)i * 2 * DI_,
        A_log + (size_t)i * 2 * DI_ * NS_, Dp + (size_t)i * 2 * DI_,
        xz_b, H0, yg_b);
    gemm_bt_bf16<64, 64, false><<<dim3(D_ / 64, L_ / 64, 1), 256, 0, stream>>>(
        yg_b, outw_b + (size_t)i * D_ * 1024, hbuf, L_, D_, 1024, 0, 0, 0);
  }

  rmsnorm_kernel<false><<<L_ / 4, 256, 0, stream>>>(residual, hbuf, norm_f_w, d_out);
}

// Round 23
// 424.178 us; speedup vs baseline: 1.0136x; 1.0136x over previous
//
#include <hip/hip_runtime.h>
#include <hip/hip_bf16.h>
#include <math.h>

#define L_  4096
#define D_  256
#define DI_ 512
#define NS_ 16
#define NC_ 128
#define CH_ 32

typedef __attribute__((ext_vector_type(8))) short short8;
typedef __attribute__((ext_vector_type(4))) short short4v;
typedef __attribute__((ext_vector_type(4))) float f32x4;

// ---------------- prep: embed + all weight converts in one dispatch ----------------
__global__ __launch_bounds__(256) void prep_kernel(const int* __restrict__ ids,
    const float* __restrict__ ew, const float* __restrict__ inw,
    const float* __restrict__ outw, const float* __restrict__ xpw,
    float* __restrict__ res, __hip_bfloat16* __restrict__ inw_b,
    __hip_bfloat16* __restrict__ outw_b, __hip_bfloat16* __restrict__ xpw_b) {
  int idx = blockIdx.x * 256 + threadIdx.x;          // 0 .. 1048575
  int l = idx >> 8, d = idx & 255;
  res[idx] = ew[ids[l] * D_ + d];
  inw_b[idx] = __float2bfloat16(inw[idx]);           // 4*1024*256 = 1048576
  {                                                  // duplicated-K out_proj [4][256][1024]
    int layer = idx >> 18;
    int rem = idx & 262143;
    int o = rem >> 10, k = rem & 1023;
    outw_b[idx] = __float2bfloat16(outw[((size_t)layer * 256 + o) * 512 + (k & 511)]);
  }
  if (idx < 4 * 2 * 64 * 512) {                      // padded [4][2][64][512]
    int layer = idx >> 16;
    int rem = idx & 65535;
    int dir = rem >> 15;
    int r = (rem >> 9) & 63, k = idx & 511;
    float v = (r < 48) ? xpw[(((size_t)layer * 2 + dir) * 48 + r) * 512 + k] : 0.f;
    xpw_b[idx] = __float2bfloat16(v);
  }
}

// ---------------- rmsnorm: wave-per-row, float4 ----------------
template<bool BF16OUT>
__global__ __launch_bounds__(256) void rmsnorm_kernel(float* __restrict__ residual,
    const float* __restrict__ hadd, const float* __restrict__ w, void* __restrict__ out) {
  int row = blockIdx.x * 4 + (threadIdx.x >> 6);
  int lane = threadIdx.x & 63;
  size_t o = (size_t)row * D_ + lane * 4;
  float4 v = *(const float4*)(residual + o);
  if (hadd) {
    float4 a = *(const float4*)(hadd + o);
    v.x += a.x; v.y += a.y; v.z += a.z; v.w += a.w;
    *(float4*)(residual + o) = v;
  }
  float sq = fmaf(v.x, v.x, fmaf(v.y, v.y, fmaf(v.z, v.z, v.w * v.w)));
  #pragma unroll
  for (int s = 32; s > 0; s >>= 1) sq += __shfl_xor(sq, s, 64);
  float scale = rsqrtf(sq * (1.f / D_) + 1e-5f);
  float4 wv = *(const float4*)(w + lane * 4);
  float r0 = v.x * scale * wv.x, r1 = v.y * scale * wv.y;
  float r2 = v.z * scale * wv.z, r3 = v.w * scale * wv.w;
  if (BF16OUT) {
    __hip_bfloat16* ob = (__hip_bfloat16*)out + o;
    short4v s4;
    s4[0] = __bfloat16_as_short(__float2bfloat16(r0));
    s4[1] = __bfloat16_as_short(__float2bfloat16(r1));
    s4[2] = __bfloat16_as_short(__float2bfloat16(r2));
    s4[3] = __bfloat16_as_short(__float2bfloat16(r3));
    *reinterpret_cast<short4v*>(ob) = s4;
  } else {
    float4 r = {r0, r1, r2, r3};
    *((float4*)out + (o >> 2)) = r;
  }
}

// ---------------- bf16 MFMA GEMM: C[m,n] = sum_k A[m,k]*B[n,k] (B^T layout) ----------------
__device__ __forceinline__ void gload_lds16(const void* g, void* l) {
  __builtin_amdgcn_global_load_lds((const __attribute__((address_space(1))) unsigned int*)g,
                                   (__attribute__((address_space(3))) unsigned int*)l,
                                   16, 0, 0);
}

template<int BM, int BN, bool BF16OUT>
__global__ __launch_bounds__(256) void gemm_bt_bf16(const __hip_bfloat16* __restrict__ A,
    const __hip_bfloat16* __restrict__ B, void* __restrict__ Cv, int M, int N, int K,
    size_t sA, size_t sB, size_t sC) {
  A += (size_t)blockIdx.z * sA; B += (size_t)blockIdx.z * sB;
  constexpr int FM = (BM / 2) / 16, FN = (BN / 2) / 16;
  constexpr int ABYTES = BM * 64, BBYTES = BN * 64;
  __shared__ __attribute__((aligned(16))) char As[ABYTES];
  __shared__ __attribute__((aligned(16))) char Bs[BBYTES];
  int tid = threadIdx.x, lane = tid & 63, w = tid >> 6;
  int bm = blockIdx.y * BM, bn = blockIdx.x * BN;
  int wr = (w >> 1) * (BM / 2), wc = (w & 1) * (BN / 2);
  f32x4 acc[FM][FN] = {};
  for (int k0 = 0; k0 < K; k0 += 32) {
    __syncthreads();
    #pragma unroll
    for (int i = 0; i < ABYTES / 4096; ++i) {
      int x = (i * 256 + tid) * 16;
      int xs = x ^ (((x >> 7) & 3) << 4);
      int row = xs >> 6, col = (xs & 63) >> 1;
      gload_lds16(A + (size_t)(bm + row) * K + k0 + col, As + i * 4096 + w * 1024);
    }
    #pragma unroll
    for (int i = 0; i < BBYTES / 4096; ++i) {
      int x = (i * 256 + tid) * 16;
      int xs = x ^ (((x >> 7) & 3) << 4);
      int row = xs >> 6, col = (xs & 63) >> 1;
      gload_lds16(B + (size_t)(bn + row) * K + k0 + col, Bs + i * 4096 + w * 1024);
    }
    __syncthreads();
    short8 af[FM], bf[FN];
    #pragma unroll
    for (int m = 0; m < FM; ++m) {
      int row = wr + m * 16 + (lane & 15);
      int x = row * 64 + ((lane >> 4) * 16);
      x ^= ((x >> 7) & 3) << 4;
      af[m] = *reinterpret_cast<const short8*>(As + x);
    }
    #pragma unroll
    for (int n = 0; n < FN; ++n) {
      int row = wc + n * 16 + (lane & 15);
      int x = row * 64 + ((lane >> 4) * 16);
      x ^= ((x >> 7) & 3) << 4;
      bf[n] = *reinterpret_cast<const short8*>(Bs + x);
    }
    #pragma unroll
    for (int m = 0; m < FM; ++m)
      #pragma unroll
      for (int n = 0; n < FN; ++n)
        acc[m][n] = __builtin_amdgcn_mfma_f32_16x16x32_bf16(af[m], bf[n], acc[m][n], 0, 0, 0);
  }
  #pragma unroll
  for (int m = 0; m < FM; ++m)
    #pragma unroll
    for (int n = 0; n < FN; ++n)
      #pragma unroll
      for (int j = 0; j < 4; ++j) {
        size_t off = (size_t)blockIdx.z * sC +
                     (size_t)(bm + wr + m * 16 + (lane >> 4) * 4 + j) * N + bn + wc + n * 16 + (lane & 15);
        if (BF16OUT) ((__hip_bfloat16*)Cv)[off] = __float2bfloat16(acc[m][n][j]);
        else         ((float*)Cv)[off] = acc[m][n][j];
      }
}

// ---------------- xproj_conv_scan: conv+SiLU -> su/uc; GEMM -> xdb; pass1 in-place ----------------
// LDS union (68.5 KB total -> 2 blocks/CU): sxz [0,36864) dead after conv;
// Bs aliased at [0,4096), sxdb at [4096,12288); su at [36864,70144).
__global__ __launch_bounds__(256) void xproj_conv_scan(const __hip_bfloat16* __restrict__ xz,
    const float* __restrict__ cw, const float* __restrict__ cb,
    const __hip_bfloat16* __restrict__ xpw_b, const float* __restrict__ dtw,
    const float* __restrict__ dtbp, const float* __restrict__ A_log,
    float* __restrict__ xdb, __hip_bfloat16* __restrict__ ucb,
    float* __restrict__ Pb, float* __restrict__ Qb) {
  int dir = blockIdx.y;
  int l0 = blockIdx.x * 32;                      // chunk c = blockIdx.x
  int tid = threadIdx.x, lane = tid & 63, w = tid >> 6;
  __shared__ __attribute__((aligned(16))) char smem[70144];
  unsigned short (*sxz)[512] = (unsigned short(*)[512])smem;          // [36][512]
  unsigned short (*su)[520]  = (unsigned short(*)[520])(smem + 36864); // [32][520]
  char* Bs = smem;                                                     // 4 KB alias
  float (*sxdb)[64] = (float(*)[64])(smem + 4096);                     // [32][64] alias
  // stage xz window: slot s holds frame l0-3+s (s=0..34; slot 35 dup, unread)
  #pragma unroll
  for (int it = 0; it < 9; ++it) {
    int s = it * 4 + w;
    int sc = s > 34 ? 34 : s;
    int f = l0 - 3 + sc;
    int row = dir ? (L_ - 1 - f) : f;
    row = row < 0 ? 0 : (row > L_ - 1 ? L_ - 1 : row);
    gload_lds16((const char*)xz + (size_t)row * 2048 + lane * 16, (char*)sxz + s * 1024);
  }
  __syncthreads();
  // u = silu(conv) -> su (bf16) + stream to global uc_b
  unsigned short* ucs = (unsigned short*)ucb;
  #pragma unroll
  for (int half = 0; half < 2; ++half) {
    int ch = half * 256 + tid;
    float4 wv = *(const float4*)(cw + ((size_t)dir * DI_ + ch) * 4);
    float bias = cb[(size_t)dir * DI_ + ch];
    #pragma unroll 4
    for (int t = 0; t < 32; ++t) {
      float acc = bias;
      #pragma unroll
      for (int k = 0; k < 4; ++k) {
        float xv = (l0 == 0 && t + k < 3) ? 0.f
                 : __uint_as_float((unsigned)sxz[t + k][ch] << 16);
        acc = fmaf(((const float*)&wv)[k], xv, acc);
      }
      float uvf = acc * __builtin_amdgcn_rcpf(1.f + __expf(-acc));
      unsigned short bits = (unsigned short)__bfloat16_as_short(__float2bfloat16(uvf));
      su[t][ch] = bits;
      ucs[((size_t)dir * L_ + l0 + t) * DI_ + ch] = bits;
    }
  }
  // GEMM: A = su (full K in LDS), B = xpw staged per k-step (Bs aliases dead sxz)
  const __hip_bfloat16* B = xpw_b + (size_t)dir * 64 * 512;
  int wr = (w >> 1) * 16, wc = (w & 1) * 32;
  f32x4 acc2[2] = {};
  for (int k0 = 0; k0 < 512; k0 += 32) {
    __syncthreads();                      // ensures all sxz reads done before Bs overwrite
    {
      int x = tid * 16;
      int xs = x ^ (((x >> 7) & 3) << 4);
      int row = xs >> 6, col = (xs & 63) >> 1;
      gload_lds16(B + (size_t)row * 512 + k0 + col, Bs + w * 1024);
    }
    __syncthreads();
    short8 af = *reinterpret_cast<const short8*>(
        (const char*)su + (wr + (lane & 15)) * 1040 + (k0 + (lane >> 4) * 8) * 2);
    #pragma unroll
    for (int n = 0; n < 2; ++n) {
      int row = wc + n * 16 + (lane & 15);
      int x = row * 64 + ((lane >> 4) * 16);
      x ^= ((x >> 7) & 3) << 4;
      short8 bf8 = *reinterpret_cast<const short8*>(Bs + x);
      acc2[n] = __builtin_amdgcn_mfma_f32_16x16x32_bf16(af, bf8, acc2[n], 0, 0, 0);
    }
  }
  // write xdb tile to global AND to LDS sxdb (aliases dead sxz region)
  #pragma unroll
  for (int n = 0; n < 2; ++n)
    #pragma unroll
    for (int j = 0; j < 4; ++j) {
      int tt = wr + (lane >> 4) * 4 + j;
      int col = wc + n * 16 + (lane & 15);
      xdb[((size_t)dir * L_ + l0 + tt) * 64 + col] = acc2[n][j];
      sxdb[tt][col] = acc2[n][j];
    }
  __syncthreads();
  // ---- pass1 in-place: 2 sequential channel halves, 16 states each ----
  size_t pqbase = ((size_t)dir * NC_ + blockIdx.x) * 8192;
  #pragma unroll
  for (int half = 0; half < 2; ++half) {
    int ch = half * 256 + tid;
    const float4* wr4 = (const float4*)(dtw + ((size_t)dir * DI_ + ch) * 16);
    float4 w0 = wr4[0], w1 = wr4[1], w2 = wr4[2], w3 = wr4[3];
    float bias = dtbp[(size_t)dir * DI_ + ch];
    const float4* Ab4 = (const float4*)(A_log + ((size_t)dir * DI_ + ch) * 16);
    float4 a0 = Ab4[0], a1 = Ab4[1], a2 = Ab4[2], a3 = Ab4[3];
    float Av[16] = {a0.x, a0.y, a0.z, a0.w, a1.x, a1.y, a1.z, a1.w,
                    a2.x, a2.y, a2.z, a2.w, a3.x, a3.y, a3.z, a3.w};
    #pragma unroll
    for (int n = 0; n < 16; ++n) Av[n] = -__expf(Av[n]);
    float P[16], Q[16];
    #pragma unroll
    for (int n = 0; n < 16; ++n) { P[n] = 1.f; Q[n] = 0.f; }
    #pragma unroll 2
    for (int t = 0; t < 32; ++t) {
      const float4* xr = (const float4*)&sxdb[t][0];
      float4 x0 = xr[0], x1 = xr[1], x2 = xr[2], x3 = xr[3];
      float accd = bias;
      accd = fmaf(w0.x, x0.x, fmaf(w0.y, x0.y, fmaf(w0.z, x0.z, fmaf(w0.w, x0.w, accd))));
      accd = fmaf(w1.x, x1.x, fmaf(w1.y, x1.y, fmaf(w1.z, x1.z, fmaf(w1.w, x1.w, accd))));
      accd = fmaf(w2.x, x2.x, fmaf(w2.y, x2.y, fmaf(w2.z, x2.z, fmaf(w2.w, x2.w, accd))));
      accd = fmaf(w3.x, x3.x, fmaf(w3.y, x3.y, fmaf(w3.z, x3.z, fmaf(w3.w, x3.w, accd))));
      float e = __expf(fminf(accd, 20.f));
      float dtv = accd > 20.f ? accd : __logf(1.f + e);
      float uv = __uint_as_float((unsigned)su[t][ch] << 16);
      float du = dtv * uv;
      const float4* Br4 = (const float4*)&sxdb[t][16];
      float4 B0 = Br4[0], B1 = Br4[1], B2 = Br4[2], B3 = Br4[3];
      float bb[16] = {B0.x, B0.y, B0.z, B0.w, B1.x, B1.y, B1.z, B1.w,
                      B2.x, B2.y, B2.z, B2.w, B3.x, B3.y, B3.z, B3.w};
      #pragma unroll
      for (int n = 0; n < 16; ++n) {
        float dA = __expf(dtv * Av[n]);
        P[n] *= dA;
        Q[n] = fmaf(dA, Q[n], bb[n] * du);
      }
    }
    #pragma unroll
    for (int n = 0; n < 16; ++n) {
      Pb[pqbase + n * 512 + ch] = P[n];
      Qb[pqbase + n * 512 + ch] = Q[n];
    }
  }
}

// ---- staging: full sxdb[32][64] + su[32][128] from global; dt computed in-LDS ----
__device__ __forceinline__ void scan_stage3(int tid, int lane, int w, int q, int dir, int c,
    const float* __restrict__ xdb, const __hip_bfloat16* __restrict__ uc,
    const float* __restrict__ dtw, const float* __restrict__ dtbp,
    float (*sxdb)[64], unsigned short (*su)[128], float (*sdt)[128]) {
  const char* bg = (const char*)(xdb + ((size_t)dir * L_ + (size_t)c * CH_) * 64);
  const char* ug = (const char*)(uc + ((size_t)dir * L_ + (size_t)c * CH_) * DI_ + q * 128);
  #pragma unroll
  for (int i = 0; i < 2; ++i)
    gload_lds16(bg + w * 2048 + i * 1024 + lane * 16, (char*)sxdb + w * 2048 + i * 1024);
  #pragma unroll
  for (int i = 0; i < 2; ++i) {
    int byte = (w * 128 + i * 64 + lane) * 16;
    gload_lds16(ug + (byte >> 8) * 1024 + (byte & 255), (char*)su + w * 2048 + i * 1024);
  }
  __syncthreads();
  int dlx = tid & 127, tst = tid >> 7;
  int dc = q * 128 + dlx;
  const float4* wr = (const float4*)(dtw + ((size_t)dir * DI_ + dc) * 16);
  float4 w0 = wr[0], w1 = wr[1], w2 = wr[2], w3 = wr[3];
  float bias = dtbp[(size_t)dir * DI_ + dc];
  #pragma unroll
  for (int i = 0; i < 16; ++i) {
    int t = tst + i * 2;
    const float4* xr = (const float4*)&sxdb[t][0];
    float4 x0 = xr[0], x1 = xr[1], x2 = xr[2], x3 = xr[3];
    float acc = bias;
    acc = fmaf(w0.x, x0.x, fmaf(w0.y, x0.y, fmaf(w0.z, x0.z, fmaf(w0.w, x0.w, acc))));
    acc = fmaf(w1.x, x1.x, fmaf(w1.y, x1.y, fmaf(w1.z, x1.z, fmaf(w1.w, x1.w, acc))));
    acc = fmaf(w2.x, x2.x, fmaf(w2.y, x2.y, fmaf(w2.z, x2.z, fmaf(w2.w, x2.w, acc))));
    acc = fmaf(w3.x, x3.x, fmaf(w3.y, x3.y, fmaf(w3.z, x3.z, fmaf(w3.w, x3.w, acc))));
    float e = __expf(fminf(acc, 20.f));
    sdt[t][dlx] = acc > 20.f ? acc : __logf(1.f + e);
  }
  __syncthreads();
}

// ---------------- combine (two-level segmented, 2 kernels): depth 128 -> 16 + (7+16) ----------------
__global__ __launch_bounds__(256) void combine_a(const float* __restrict__ Pb,
    const float* __restrict__ Qb, float* __restrict__ Pseg, float* __restrict__ Qseg) {
  int chain = blockIdx.x * 256 + threadIdx.x;   // 0..16383
  int seg = blockIdx.y;                          // 0..7
  int dir = chain >> 13, s = chain & 8191;
  size_t base = (size_t)dir * NC_ * 8192 + s;
  float P = 1.f, Q = 0.f;
  #pragma unroll 16
  for (int cc = 0; cc < 16; ++cc) {
    size_t o = base + (size_t)(seg * 16 + cc) * 8192;
    float p = Pb[o], q = Qb[o];
    Q = fmaf(p, Q, q);
    P *= p;
  }
  Pseg[seg * 16384 + chain] = P;
  Qseg[seg * 16384 + chain] = Q;
}

__global__ __launch_bounds__(256) void combine_c(const float* __restrict__ Pb,
    const float* __restrict__ Qb, const float* __restrict__ Pseg,
    const float* __restrict__ Qseg, float* __restrict__ H0) {
  int chain = blockIdx.x * 256 + threadIdx.x;
  int seg = blockIdx.y;
  int dir = chain >> 13, s = chain & 8191;
  size_t base = (size_t)dir * NC_ * 8192 + s;
  float h = 0.f;
  for (int s2 = 0; s2 < seg; ++s2)
    h = fmaf(Pseg[s2 * 16384 + chain], h, Qseg[s2 * 16384 + chain]);
  #pragma unroll 16
  for (int cc = 0; cc < 16; ++cc) {
    size_t o = base + (size_t)(seg * 16 + cc) * 8192;
    H0[o] = h;
    h = fmaf(Pb[o], h, Qb[o]);
  }
}

// ---------------- scan pass2 ----------------
__global__ __launch_bounds__(256) void scan_pass2(const __hip_bfloat16* __restrict__ uc,
    const float* __restrict__ xdb, const float* __restrict__ dtw,
    const float* __restrict__ dtbp, const float* __restrict__ A_log,
    const float* __restrict__ Dp, const __hip_bfloat16* __restrict__ xz,
    const float* __restrict__ H0, __hip_bfloat16* __restrict__ yg) {
  int dir = blockIdx.y;
  int c = blockIdx.x >> 2, q = blockIdx.x & 3;
  int tid = threadIdx.x, lane = tid & 63, w = tid >> 6;
  int dl = tid >> 1, nh = tid & 1;
  int d = q * 128 + dl;
  __shared__ __attribute__((aligned(16))) float sxdb[CH_][64];
  __shared__ __attribute__((aligned(16))) unsigned short su[CH_][128];
  __shared__ __attribute__((aligned(16))) float sdt[CH_][128];
  float Av[8], h[8];
  const float4* Ab4 = (const float4*)(A_log + ((size_t)dir * DI_ + d) * 16 + nh * 8);
  float4 a0 = Ab4[0], a1 = Ab4[1];
  float al[8] = {a0.x, a0.y, a0.z, a0.w, a1.x, a1.y, a1.z, a1.w};
  size_t ob = ((size_t)dir * NC_ + c) * 8192 + (size_t)(nh * 8) * 512 + d;
  #pragma unroll
  for (int j = 0; j < 8; ++j) { Av[j] = -__expf(al[j]); h[j] = H0[ob + j * 512]; }
  float Dv = Dp[(size_t)dir * DI_ + d];
  scan_stage3(tid, lane, w, q, dir, c, xdb, uc, dtw, dtbp, sxdb, su, sdt);
  #pragma unroll 8
  for (int t = 0; t < CH_; ++t) {
    float dtv = sdt[t][dl];
    float uv  = __uint_as_float((unsigned)su[t][dl] << 16);
    float du = dtv * uv;
    const float4* Br = (const float4*)&sxdb[t][16 + nh * 8];
    const float4* Cr = (const float4*)&sxdb[t][32 + nh * 8];
    float4 b0 = Br[0], b1 = Br[1], c0 = Cr[0], c1 = Cr[1];
    float bb[8] = {b0.x, b0.y, b0.z, b0.w, b1.x, b1.y, b1.z, b1.w};
    float cc[8] = {c0.x, c0.y, c0.z, c0.w, c1.x, c1.y, c1.z, c1.w};
    float y = 0.f;
    #pragma unroll
    for (int j = 0; j < 8; ++j) {
      float dA = __expf(dtv * Av[j]);
      h[j] = fmaf(dA, h[j], bb[j] * du);
      y = fmaf(h[j], cc[j], y);
    }
    y += __shfl_xor(y, 1, 64);
    if (nh == 0) {
      int l = c * CH_ + t;
      int pos = dir ? (L_ - 1 - l) : l;
      float zv = __bfloat162float(xz[(size_t)pos * 1024 + DI_ + d]);
      float g = zv * __builtin_amdgcn_rcpf(1.f + __expf(-zv));
      yg[(size_t)pos * 1024 + (size_t)dir * DI_ + d] = __float2bfloat16((y + uv * Dv) * g);
    }
  }
}

extern "C" void kernel_launch(void* const* d_in, const int* in_sizes, int n_in,
                              void* d_out, int out_size, void* d_ws, size_t ws_size,
                              hipStream_t stream) {
  const int*   ids       = (const int*)  d_in[0];
  const float* embed_w   = (const float*)d_in[1];
  const float* norm_w    = (const float*)d_in[2];
  const float* in_proj_w = (const float*)d_in[3];
  const float* out_proj_w= (const float*)d_in[4];
  const float* conv_w    = (const float*)d_in[5];
  const float* conv_b    = (const float*)d_in[6];
  const float* x_proj_w  = (const float*)d_in[7];
  const float* dt_proj_w = (const float*)d_in[8];
  const float* dt_proj_b = (const float*)d_in[9];
  const float* A_log     = (const float*)d_in[10];
  const float* Dp        = (const float*)d_in[11];
  const float* norm_f_w  = (const float*)d_in[12];

  float* ws = (float*)d_ws;
  float* residual = ws; ws += (size_t)L_ * D_;
  float* xdb      = ws; ws += (size_t)2 * L_ * 64;
  float* hbuf     = ws; ws += (size_t)L_ * D_;
  float* Pb       = ws; ws += (size_t)2 * NC_ * 8192;
  float* Qb       = ws; ws += (size_t)2 * NC_ * 8192;
  float* H0       = ws; ws += (size_t)2 * NC_ * 8192;
  float* Pseg     = ws; ws += (size_t)8 * 16384;
  float* Qseg     = ws; ws += (size_t)8 * 16384;
  __hip_bfloat16* hn_b   = (__hip_bfloat16*)ws;
  __hip_bfloat16* xz_b   = hn_b + (size_t)L_ * D_;
  __hip_bfloat16* yg_b   = xz_b + (size_t)L_ * 1024;     // [pos][dir*512+d]
  __hip_bfloat16* uc_b   = yg_b + (size_t)L_ * 1024;
  __hip_bfloat16* inw_b  = uc_b + (size_t)2 * L_ * DI_;
  __hip_bfloat16* outw_b = inw_b + (size_t)4 * 1024 * D_;
  __hip_bfloat16* xpw_b  = outw_b + (size_t)4 * D_ * 1024;

  prep_kernel<<<L_ * D_ / 256, 256, 0, stream>>>(ids, embed_w, in_proj_w, out_proj_w,
                                                 x_proj_w, residual, inw_b, outw_b, xpw_b);

  for (int i = 0; i < 4; ++i) {
    rmsnorm_kernel<true><<<L_ / 4, 256, 0, stream>>>(residual, i ? hbuf : nullptr,
                                                     norm_w + (size_t)i * D_, hn_b);
    gemm_bt_bf16<128, 64, true><<<dim3(1024 / 64, L_ / 128, 1), 256, 0, stream>>>(
        hn_b, inw_b + (size_t)i * 1024 * D_, xz_b, L_, 1024, D_, 0, 0, 0);
    xproj_conv_scan<<<dim3(L_ / 32, 2), 256, 0, stream>>>(
        xz_b, conv_w + (size_t)i * 2 * DI_ * 4, conv_b + (size_t)i * 2 * DI_,
        xpw_b + (size_t)i * 2 * 64 * DI_, dt_proj_w + (size_t)i * 2 * DI_ * 16,
        dt_proj_b + (size_t)i * 2 * DI_, A_log + (size_t)i * 2 * DI_ * NS_,
        xdb, uc_b, Pb, Qb);
    combine_a<<<dim3(64, 8), 256, 0, stream>>>(Pb, Qb, Pseg, Qseg);
    combine_c<<<dim3(64, 8), 256, 0, stream>>>(Pb, Qb, Pseg, Qseg, H0);
    scan_pass2<<<dim3(NC_ * 4, 2), 256, 0, stream>>>(
        uc_b, xdb, dt_proj_w + (size_t)i * 2 * DI_ * 16, dt_proj_b + (size_t)i * 2 * DI_,
        A_log + (size_t)i * 2 * DI_ * NS_, Dp + (size_t)i * 2 * DI_,
        xz_b, H0, yg_b);
    gemm_bt_bf16<64, 64, false><<<dim3(D_ / 64, L_ / 64, 1), 256, 0, stream>>>(
        yg_b, outw_b + (size_t)i * D_ * 1024, hbuf, L_, D_, 1024, 0, 0, 0);
  }

  rmsnorm_kernel<false><<<L_ / 4, 256, 0, stream>>>(residual, hbuf, norm_f_w, d_out);
}